// Round 7
// baseline (201.707 us; speedup 1.0000x reference)
//
#include <hip/hip_runtime.h>

// Problem constants
#define BB 2
#define NRES 192
#define NATOMS 4
#define NN 768            // N = NRES*NATOMS
#define NODE_DIM 128
#define EDGE_DIM 64
#define NUM_RBF 32
#define NROWS (BB * NN)   // 1536

// Output layout (float32 elements, concatenated flat in return order)
#define NODE_OFF   ((size_t)0)
#define EDGE_OFF   ((size_t)196608)                 // 2*768*128
#define COORDS_OFF ((size_t)(196608 + 75497472))    // + 2*768*768*64
#define MASK_OFF   ((size_t)(COORDS_OFF + 4608))    // + 2*768*3

__device__ __forceinline__ float silu(float x) { return x / (1.0f + expf(-x)); }

// ---------------------------------------------------------------------------
// Node kernel: one block (128 threads) per residue (B*NRES = 384 blocks).
// ---------------------------------------------------------------------------
__global__ __launch_bounds__(128) void node_kernel(
    const float* __restrict__ coords,
    const float* __restrict__ mut_mask,
    const float* __restrict__ atom_mask,
    const float* __restrict__ aa_emb,
    const float* __restrict__ atom_emb,
    const float* __restrict__ pos_emb,
    const float* __restrict__ aa_props,
    const float* __restrict__ mW1, const float* __restrict__ mb1,
    const float* __restrict__ mW2, const float* __restrict__ mb2,
    const float* __restrict__ nW1, const float* __restrict__ nb1,
    const float* __restrict__ nW2, const float* __restrict__ nb2,
    const int* __restrict__ wt_idx, const int* __restrict__ mut_idx,
    const int* __restrict__ res_idx,
    float* __restrict__ out)
{
    __shared__ float s_in[128];   // mut_in (124 used)
    __shared__ float s_h[128];    // hidden (64 or 128 used)
    __shared__ float s_res[96];   // res_feat (94 used)
    __shared__ float s_nin[128];  // node_in (126 used)

    const int blk = blockIdx.x;   // b*192 + r
    const int t = threadIdx.x;

    const int wt = wt_idx[blk];
    const int mu = mut_idx[blk];
    const float mm = mut_mask[blk];

    if (t < 32) { s_in[t] = aa_emb[wt * 32 + t]; s_in[32 + t] = aa_emb[mu * 32 + t]; }
    if (t < 30) { s_in[64 + t] = aa_props[wt * 30 + t]; s_in[94 + t] = aa_props[mu * 30 + t]; }
    __syncthreads();

    if (t < 64) {
        float acc = mb1[t];
        for (int k = 0; k < 124; ++k) acc += s_in[k] * mW1[k * 64 + t];
        s_h[t] = silu(acc);
    }
    __syncthreads();

    if (t < 32) {
        float acc = mb2[t];
        for (int k = 0; k < 64; ++k) acc += s_h[k] * mW2[k * 32 + t];
        s_res[62 + t] = acc * mm;
        s_res[t] = s_in[t];
    }
    if (t < 30) s_res[32 + t] = s_in[64 + t];
    __syncthreads();

    for (int a = 0; a < 4; ++a) {
        const int gn = blk * 4 + a;   // b*768 + n
        if (t < 94) s_nin[t] = s_res[t];
        else if (t < 110) s_nin[t] = atom_emb[a * 16 + (t - 94)];
        else if (t < 126) s_nin[t] = pos_emb[res_idx[gn] * 16 + (t - 110)];
        __syncthreads();

        float acc = nb1[t];
        for (int k = 0; k < 126; ++k) acc += s_nin[k] * nW1[k * 128 + t];
        float h = silu(acc);
        __syncthreads();
        s_h[t] = h;
        __syncthreads();

        float o = nb2[t];
        for (int k = 0; k < 128; ++k) o += s_h[k] * nW2[k * 128 + t];
        const float am = atom_mask[gn];
        out[NODE_OFF + (size_t)gn * 128 + t] = o * am;
        __syncthreads();
    }

    if (t < 12) out[COORDS_OFF + (size_t)blk * 12 + t] = coords[(size_t)blk * 12 + t];
    if (t < 4)  out[MASK_OFF + (size_t)blk * 4 + t]  = atom_mask[(size_t)blk * 4 + t];
}

// ---------------------------------------------------------------------------
// edge_all_kernel: single-pass streaming writer + inline sparse MLP.
// Grid-stride, one 16B chunk (4 channels) per thread per iter. Each 16-lane
// group of a wave covers exactly one (row, j) sub-row (16 consecutive
// chunks). Group recomputes adjacency from coords; non-adjacent -> zero
// store; adjacent -> cooperative MLP: lane s computes hidden h in
// {s, s+16, s+32, s+48} from LDS-staged W1, broadcasts via __shfl, and
// accumulates its own 4 output channels from LDS-staged W2.
// ---------------------------------------------------------------------------
__global__ __launch_bounds__(256) void edge_all_kernel(
    const float* __restrict__ coords,
    const float* __restrict__ atom_mask,
    const float* __restrict__ eW1, const float* __restrict__ eb1,
    const float* __restrict__ eW2, const float* __restrict__ eb2,
    float* __restrict__ out)
{
    __shared__ float sW1[NUM_RBF * 64];   // 8 KB
    __shared__ float sW2[64 * EDGE_DIM];  // 16 KB
    __shared__ float sb1[64], sb2[64];    // 0.5 KB

    const int t = threadIdx.x;
    for (int k = t; k < NUM_RBF * 64; k += 256) sW1[k] = eW1[k];
    for (int k = t; k < 64 * EDGE_DIM; k += 256) sW2[k] = eW2[k];
    if (t < 64) { sb1[t] = eb1[t]; sb2[t] = eb2[t]; }
    __syncthreads();

    const int lane = t & 63;
    const int s = lane & 15;          // sub-lane within 16-group
    const int gb = lane & 48;         // group base lane

    const size_t total = (size_t)NROWS * NN * (EDGE_DIM / 4);   // 16B chunks
    float4* ep = (float4*)(out + EDGE_OFF);

    for (size_t q = (size_t)blockIdx.x * 256 + t; q < total;
         q += (size_t)gridDim.x * 256) {
        const int subrow = (int)(q >> 4);       // row*NN + j  (< 1,179,648)
        const int row = subrow / NN;            // const-divisor magic mul
        const int j = subrow - row * NN;
        const int b = (row >= NN) ? 1 : 0;
        const int i = row - b * NN;

        const float* cb = coords + (size_t)b * NN * 3;
        const float* mb = atom_mask + (size_t)b * NN;
        const float dx = cb[i * 3 + 0] - cb[j * 3 + 0];
        const float dy = cb[i * 3 + 1] - cb[j * 3 + 1];
        const float dz = cb[i * 3 + 2] - cb[j * 3 + 2];
        const float d2 = dx * dx + dy * dy + dz * dz + 1e-8f;
        const float mf = mb[i] * mb[j];
        const bool adj = (d2 <= 56.25f) && (i != j) && (mf != 0.0f);

        if (!adj) {
            ep[q] = make_float4(0.f, 0.f, 0.f, 0.f);
        } else {
            const float d = sqrtf(d2);
            // per-lane full RBF vector (32 exps, hw-rate)
            float rbf[NUM_RBF];
            #pragma unroll
            for (int k = 0; k < NUM_RBF; ++k) {
                const float dd = d - (float)k * (20.0f / 31.0f);
                rbf[k] = __expf(-(dd * dd) * (1.0f / 0.78125f));  // 2*gamma^2
            }
            // lane s owns hidden h = s + 16*hh
            float hid[4];
            #pragma unroll
            for (int hh = 0; hh < 4; ++hh) {
                const int h = s + 16 * hh;
                float a0 = 0.f, a1 = 0.f, a2 = 0.f, a3 = 0.f;
                #pragma unroll
                for (int k = 0; k < NUM_RBF; k += 4) {
                    a0 += rbf[k]     * sW1[(k)     * 64 + h];
                    a1 += rbf[k + 1] * sW1[(k + 1) * 64 + h];
                    a2 += rbf[k + 2] * sW1[(k + 2) * 64 + h];
                    a3 += rbf[k + 3] * sW1[(k + 3) * 64 + h];
                }
                hid[hh] = silu(sb1[h] + ((a0 + a1) + (a2 + a3)));
            }
            // this lane's 4 output channels
            const int c0 = ((int)q & 15) * 4;
            float o0 = sb2[c0], o1 = sb2[c0 + 1], o2 = sb2[c0 + 2], o3 = sb2[c0 + 3];
            #pragma unroll
            for (int h = 0; h < 64; ++h) {
                const float hv = __shfl(hid[h >> 4], gb + (h & 15));
                const float4 w4 = *(const float4*)&sW2[h * EDGE_DIM + c0];
                o0 += hv * w4.x;
                o1 += hv * w4.y;
                o2 += hv * w4.z;
                o3 += hv * w4.w;
            }
            ep[q] = make_float4(o0 * mf, o1 * mf, o2 * mf, o3 * mf);
        }
    }
}

extern "C" void kernel_launch(void* const* d_in, const int* in_sizes, int n_in,
                              void* d_out, int out_size, void* d_ws, size_t ws_size,
                              hipStream_t stream) {
    const float* coords    = (const float*)d_in[0];
    const float* mut_mask  = (const float*)d_in[1];
    const float* atom_mask = (const float*)d_in[2];
    const float* aa_emb    = (const float*)d_in[3];
    const float* atom_emb  = (const float*)d_in[4];
    const float* pos_emb   = (const float*)d_in[5];
    const float* aa_props  = (const float*)d_in[6];
    const float* mut_W1    = (const float*)d_in[7];
    const float* mut_b1    = (const float*)d_in[8];
    const float* mut_W2    = (const float*)d_in[9];
    const float* mut_b2    = (const float*)d_in[10];
    const float* node_W1   = (const float*)d_in[11];
    const float* node_b1   = (const float*)d_in[12];
    const float* node_W2   = (const float*)d_in[13];
    const float* node_b2   = (const float*)d_in[14];
    const float* edge_W1   = (const float*)d_in[15];
    const float* edge_b1   = (const float*)d_in[16];
    const float* edge_W2   = (const float*)d_in[17];
    const float* edge_b2   = (const float*)d_in[18];
    const int* wt_indices  = (const int*)d_in[19];
    const int* mut_indices = (const int*)d_in[20];
    const int* res_indices = (const int*)d_in[21];

    float* out = (float*)d_out;

    node_kernel<<<BB * NRES, 128, 0, stream>>>(
        coords, mut_mask, atom_mask, aa_emb, atom_emb, pos_emb, aa_props,
        mut_W1, mut_b1, mut_W2, mut_b2, node_W1, node_b1, node_W2, node_b2,
        wt_indices, mut_indices, res_indices, out);

    edge_all_kernel<<<2048, 256, 0, stream>>>(
        coords, atom_mask, edge_W1, edge_b1, edge_W2, edge_b2, out);
}

// Round 8
// 136.530 us; speedup vs baseline: 1.4774x; 1.4774x over previous
//
#include <hip/hip_runtime.h>

// Problem constants
#define BB 2
#define NRES 192
#define NATOMS 4
#define NN 768            // N = NRES*NATOMS
#define NODE_DIM 128
#define EDGE_DIM 64
#define NUM_RBF 32
#define NROWS (BB * NN)   // 1536

// Output layout (float32 elements, concatenated flat in return order)
#define NODE_OFF   ((size_t)0)
#define EDGE_OFF   ((size_t)196608)                 // 2*768*128
#define COORDS_OFF ((size_t)(196608 + 75497472))    // + 2*768*768*64
#define MASK_OFF   ((size_t)(COORDS_OFF + 4608))    // + 2*768*3
#define EDGE_BYTES ((size_t)NROWS * NN * EDGE_DIM * 4)   // 301,989,888

__device__ __forceinline__ float silu(float x) { return x / (1.0f + expf(-x)); }

// ---------------------------------------------------------------------------
// Node kernel: one block (128 threads) per residue (B*NRES = 384 blocks).
// Writes node_features + coords_flat + atom_mask_flat (disjoint from edge).
// ---------------------------------------------------------------------------
__global__ __launch_bounds__(128) void node_kernel(
    const float* __restrict__ coords,
    const float* __restrict__ mut_mask,
    const float* __restrict__ atom_mask,
    const float* __restrict__ aa_emb,
    const float* __restrict__ atom_emb,
    const float* __restrict__ pos_emb,
    const float* __restrict__ aa_props,
    const float* __restrict__ mW1, const float* __restrict__ mb1,
    const float* __restrict__ mW2, const float* __restrict__ mb2,
    const float* __restrict__ nW1, const float* __restrict__ nb1,
    const float* __restrict__ nW2, const float* __restrict__ nb2,
    const int* __restrict__ wt_idx, const int* __restrict__ mut_idx,
    const int* __restrict__ res_idx,
    float* __restrict__ out)
{
    __shared__ float s_in[128];   // mut_in (124 used)
    __shared__ float s_h[128];    // hidden (64 or 128 used)
    __shared__ float s_res[96];   // res_feat (94 used)
    __shared__ float s_nin[128];  // node_in (126 used)

    const int blk = blockIdx.x;   // b*192 + r
    const int t = threadIdx.x;

    const int wt = wt_idx[blk];
    const int mu = mut_idx[blk];
    const float mm = mut_mask[blk];

    if (t < 32) { s_in[t] = aa_emb[wt * 32 + t]; s_in[32 + t] = aa_emb[mu * 32 + t]; }
    if (t < 30) { s_in[64 + t] = aa_props[wt * 30 + t]; s_in[94 + t] = aa_props[mu * 30 + t]; }
    __syncthreads();

    if (t < 64) {
        float acc = mb1[t];
        for (int k = 0; k < 124; ++k) acc += s_in[k] * mW1[k * 64 + t];
        s_h[t] = silu(acc);
    }
    __syncthreads();

    if (t < 32) {
        float acc = mb2[t];
        for (int k = 0; k < 64; ++k) acc += s_h[k] * mW2[k * 32 + t];
        s_res[62 + t] = acc * mm;
        s_res[t] = s_in[t];
    }
    if (t < 30) s_res[32 + t] = s_in[64 + t];
    __syncthreads();

    for (int a = 0; a < 4; ++a) {
        const int gn = blk * 4 + a;   // b*768 + n
        if (t < 94) s_nin[t] = s_res[t];
        else if (t < 110) s_nin[t] = atom_emb[a * 16 + (t - 94)];
        else if (t < 126) s_nin[t] = pos_emb[res_idx[gn] * 16 + (t - 110)];
        __syncthreads();

        float acc = nb1[t];
        for (int k = 0; k < 126; ++k) acc += s_nin[k] * nW1[k * 128 + t];
        float h = silu(acc);
        __syncthreads();
        s_h[t] = h;
        __syncthreads();

        float o = nb2[t];
        for (int k = 0; k < 128; ++k) o += s_h[k] * nW2[k * 128 + t];
        const float am = atom_mask[gn];
        out[NODE_OFF + (size_t)gn * 128 + t] = o * am;
        __syncthreads();
    }

    if (t < 12) out[COORDS_OFF + (size_t)blk * 12 + t] = coords[(size_t)blk * 12 + t];
    if (t < 4)  out[MASK_OFF + (size_t)blk * 4 + t]  = atom_mask[(size_t)blk * 4 + t];
}

// ---------------------------------------------------------------------------
// edge_mlp_kernel: one block (256 threads) per row (b,i).
// Ballot-compacts adjacent j's into an LDS list, then one lane per pair
// computes the 32->64->64 MLP (wave-uniform global weight reads, 4 partial
// accumulation chains) and overwrites that pair's pre-zeroed 256B sub-row.
// Runs after the edge-region memset on the same stream.
// ---------------------------------------------------------------------------
__global__ __launch_bounds__(256) void edge_mlp_kernel(
    const float* __restrict__ coords,
    const float* __restrict__ atom_mask,
    const float* __restrict__ eW1, const float* __restrict__ eb1,
    const float* __restrict__ eW2, const float* __restrict__ eb2,
    float* __restrict__ out)
{
    __shared__ int s_list[NN];
    __shared__ int s_cnt;

    const int row = blockIdx.x;        // b*NN + i
    const int b = row / NN;
    const int i = row % NN;
    const int t = threadIdx.x;
    const int lane = t & 63;

    if (t == 0) s_cnt = 0;
    __syncthreads();

    const float* cb = coords + (size_t)b * NN * 3;
    const float* mb = atom_mask + (size_t)b * NN;
    const float xi = cb[i * 3 + 0], yi = cb[i * 3 + 1], zi = cb[i * 3 + 2];
    const float mi = mb[i];

    for (int r = 0; r < 3; ++r) {
        const int j = t + r * 256;
        const float dx = xi - cb[j * 3 + 0];
        const float dy = yi - cb[j * 3 + 1];
        const float dz = zi - cb[j * 3 + 2];
        const float d2 = dx * dx + dy * dy + dz * dz + 1e-8f;
        const float mprod = mi * mb[j];
        const bool adj = (d2 <= 7.5f * 7.5f) && (j != i) && (mprod != 0.0f);
        const unsigned long long bal = __ballot(adj);
        const int lofs = __popcll(bal & ((1ull << lane) - 1ull));
        int base = 0;
        if (lane == 0 && bal) base = atomicAdd(&s_cnt, __popcll(bal));
        base = __shfl(base, 0);
        if (adj) s_list[base + lofs] = j;
    }
    __syncthreads();

    const int cnt = s_cnt;
    float* rowp = out + EDGE_OFF + (size_t)row * (size_t)NN * EDGE_DIM;

    for (int idx = t; idx < cnt; idx += 256) {
        const int j = s_list[idx];
        const float dx = xi - cb[j * 3 + 0];
        const float dy = yi - cb[j * 3 + 1];
        const float dz = zi - cb[j * 3 + 2];
        const float d = sqrtf(dx * dx + dy * dy + dz * dz + 1e-8f);
        const float mf = mi * mb[j];

        float rbf[NUM_RBF];
        #pragma unroll
        for (int k = 0; k < NUM_RBF; ++k) {
            const float dd = d - (float)k * (20.0f / 31.0f);
            rbf[k] = expf(-(dd * dd) / 0.78125f);   // 2*gamma^2, gamma=0.625
        }

        float o[EDGE_DIM];
        #pragma unroll
        for (int c = 0; c < EDGE_DIM; c += 4) {
            const float4 bb4 = *(const float4*)&eb2[c];
            o[c] = bb4.x; o[c + 1] = bb4.y; o[c + 2] = bb4.z; o[c + 3] = bb4.w;
        }

        for (int h = 0; h < 64; ++h) {             // wave-uniform weight reads
            float a0 = 0.f, a1 = 0.f, a2 = 0.f, a3 = 0.f;
            #pragma unroll
            for (int k = 0; k < NUM_RBF; k += 4) {
                a0 += rbf[k]     * eW1[(k)     * 64 + h];
                a1 += rbf[k + 1] * eW1[(k + 1) * 64 + h];
                a2 += rbf[k + 2] * eW1[(k + 2) * 64 + h];
                a3 += rbf[k + 3] * eW1[(k + 3) * 64 + h];
            }
            const float hv = silu(eb1[h] + ((a0 + a1) + (a2 + a3)));
            #pragma unroll
            for (int c = 0; c < EDGE_DIM; c += 4) {
                const float4 w4 = *(const float4*)&eW2[h * 64 + c];
                o[c]     += hv * w4.x;
                o[c + 1] += hv * w4.y;
                o[c + 2] += hv * w4.z;
                o[c + 3] += hv * w4.w;
            }
        }

        float* pp = rowp + (size_t)j * EDGE_DIM;
        #pragma unroll
        for (int q = 0; q < EDGE_DIM / 4; ++q) {
            ((float4*)pp)[q] = make_float4(o[4 * q] * mf, o[4 * q + 1] * mf,
                                           o[4 * q + 2] * mf, o[4 * q + 3] * mf);
        }
    }
}

extern "C" void kernel_launch(void* const* d_in, const int* in_sizes, int n_in,
                              void* d_out, int out_size, void* d_ws, size_t ws_size,
                              hipStream_t stream) {
    const float* coords    = (const float*)d_in[0];
    const float* mut_mask  = (const float*)d_in[1];
    const float* atom_mask = (const float*)d_in[2];
    const float* aa_emb    = (const float*)d_in[3];
    const float* atom_emb  = (const float*)d_in[4];
    const float* pos_emb   = (const float*)d_in[5];
    const float* aa_props  = (const float*)d_in[6];
    const float* mut_W1    = (const float*)d_in[7];
    const float* mut_b1    = (const float*)d_in[8];
    const float* mut_W2    = (const float*)d_in[9];
    const float* mut_b2    = (const float*)d_in[10];
    const float* node_W1   = (const float*)d_in[11];
    const float* node_b1   = (const float*)d_in[12];
    const float* node_W2   = (const float*)d_in[13];
    const float* node_b2   = (const float*)d_in[14];
    const float* edge_W1   = (const float*)d_in[15];
    const float* edge_b1   = (const float*)d_in[16];
    const float* edge_W2   = (const float*)d_in[17];
    const float* edge_b2   = (const float*)d_in[18];
    const int* wt_indices  = (const int*)d_in[19];
    const int* mut_indices = (const int*)d_in[20];
    const int* res_indices = (const int*)d_in[21];

    float* out = (float*)d_out;

    // 1) zero exactly the edge region (302.0 MB) at blit rate
    (void)hipMemsetAsync((char*)d_out + EDGE_OFF * 4, 0, EDGE_BYTES, stream);

    // 2) node features + coords/mask passthrough (disjoint output regions)
    node_kernel<<<BB * NRES, 128, 0, stream>>>(
        coords, mut_mask, atom_mask, aa_emb, atom_emb, pos_emb, aa_props,
        mut_W1, mut_b1, mut_W2, mut_b2, node_W1, node_b1, node_W2, node_b2,
        wt_indices, mut_indices, res_indices, out);

    // 3) sparse edge MLP overwrite (adjacency recomputed inline)
    edge_mlp_kernel<<<NROWS, 256, 0, stream>>>(
        coords, atom_mask, edge_W1, edge_b1, edge_W2, edge_b2, out);
}

// Round 9
// 126.299 us; speedup vs baseline: 1.5971x; 1.0810x over previous
//
#include <hip/hip_runtime.h>

// Problem constants
#define BB 2
#define NRES 192
#define NATOMS 4
#define NN 768            // N = NRES*NATOMS
#define NODE_DIM 128
#define EDGE_DIM 64
#define NUM_RBF 32
#define NROWS (BB * NN)   // 1536
#define NODE_BLOCKS (BB * NRES / 2)   // 192 blocks, 2 residues each

// Output layout (float32 elements, concatenated flat in return order)
#define NODE_OFF   ((size_t)0)
#define EDGE_OFF   ((size_t)196608)                 // 2*768*128
#define COORDS_OFF ((size_t)(196608 + 75497472))    // + 2*768*768*64
#define MASK_OFF   ((size_t)(COORDS_OFF + 4608))    // + 2*768*3
#define EDGE_BYTES ((size_t)NROWS * NN * EDGE_DIM * 4)   // 301,989,888

typedef float f32x4 __attribute__((ext_vector_type(4)));

__device__ __forceinline__ float silu(float x) { return x / (1.0f + expf(-x)); }

// ---------------------------------------------------------------------------
// fused_kernel: one dispatch after the edge-region memset.
//   blocks [0, NROWS)             : edge row (b,i) — ballot-compact adjacent
//                                   j's, one lane per pair runs the 32->64->64
//                                   MLP, nontemporal-overwrites the 256B
//                                   sub-row.
//   blocks [NROWS, NROWS+192)     : node path, 2 residues per block
//                                   (t<128 -> residue 2r, t>=128 -> 2r+1);
//                                   both halves execute identical sync
//                                   sequences (uniform control flow).
// ---------------------------------------------------------------------------
__global__ __launch_bounds__(256) void fused_kernel(
    const float* __restrict__ coords,
    const float* __restrict__ mut_mask,
    const float* __restrict__ atom_mask,
    const float* __restrict__ aa_emb,
    const float* __restrict__ atom_emb,
    const float* __restrict__ pos_emb,
    const float* __restrict__ aa_props,
    const float* __restrict__ mW1, const float* __restrict__ mb1,
    const float* __restrict__ mW2, const float* __restrict__ mb2,
    const float* __restrict__ nW1, const float* __restrict__ nb1,
    const float* __restrict__ nW2, const float* __restrict__ nb2,
    const float* __restrict__ eW1, const float* __restrict__ eb1,
    const float* __restrict__ eW2, const float* __restrict__ eb2,
    const int* __restrict__ wt_idx, const int* __restrict__ mut_idx,
    const int* __restrict__ res_idx,
    float* __restrict__ out)
{
    __shared__ union {
        struct {               // edge path
            int list[NN];
            int cnt;
        } e;
        struct {               // node path (2 residues)
            float in[2][128];
            float h[2][128];
            float res[2][96];
            float nin[2][128];
        } n;
    } sm;

    const int blk = blockIdx.x;
    const int t = threadIdx.x;

    if (blk < NROWS) {
        // ================= edge path =================
        const int row = blk;               // b*NN + i
        const int b = row / NN;
        const int i = row % NN;
        const int lane = t & 63;

        if (t == 0) sm.e.cnt = 0;
        __syncthreads();

        const float* cb = coords + (size_t)b * NN * 3;
        const float* mb = atom_mask + (size_t)b * NN;
        const float xi = cb[i * 3 + 0], yi = cb[i * 3 + 1], zi = cb[i * 3 + 2];
        const float mi = mb[i];

        for (int r = 0; r < 3; ++r) {
            const int j = t + r * 256;
            const float dx = xi - cb[j * 3 + 0];
            const float dy = yi - cb[j * 3 + 1];
            const float dz = zi - cb[j * 3 + 2];
            const float d2 = dx * dx + dy * dy + dz * dz + 1e-8f;
            const float mprod = mi * mb[j];
            const bool adj = (d2 <= 7.5f * 7.5f) && (j != i) && (mprod != 0.0f);
            const unsigned long long bal = __ballot(adj);
            const int lofs = __popcll(bal & ((1ull << lane) - 1ull));
            int base = 0;
            if (lane == 0 && bal) base = atomicAdd(&sm.e.cnt, __popcll(bal));
            base = __shfl(base, 0);
            if (adj) sm.e.list[base + lofs] = j;
        }
        __syncthreads();

        const int cnt = sm.e.cnt;
        float* rowp = out + EDGE_OFF + (size_t)row * (size_t)NN * EDGE_DIM;

        for (int idx = t; idx < cnt; idx += 256) {
            const int j = sm.e.list[idx];
            const float dx = xi - cb[j * 3 + 0];
            const float dy = yi - cb[j * 3 + 1];
            const float dz = zi - cb[j * 3 + 2];
            const float d = sqrtf(dx * dx + dy * dy + dz * dz + 1e-8f);
            const float mf = mi * mb[j];

            float rbf[NUM_RBF];
            #pragma unroll
            for (int k = 0; k < NUM_RBF; ++k) {
                const float dd = d - (float)k * (20.0f / 31.0f);
                rbf[k] = expf(-(dd * dd) / 0.78125f);   // 2*gamma^2, gamma=0.625
            }

            float o[EDGE_DIM];
            #pragma unroll
            for (int c = 0; c < EDGE_DIM; c += 4) {
                const float4 bb4 = *(const float4*)&eb2[c];
                o[c] = bb4.x; o[c + 1] = bb4.y; o[c + 2] = bb4.z; o[c + 3] = bb4.w;
            }

            for (int h = 0; h < 64; ++h) {             // wave-uniform weight reads
                float a0 = 0.f, a1 = 0.f, a2 = 0.f, a3 = 0.f;
                #pragma unroll
                for (int k = 0; k < NUM_RBF; k += 4) {
                    a0 += rbf[k]     * eW1[(k)     * 64 + h];
                    a1 += rbf[k + 1] * eW1[(k + 1) * 64 + h];
                    a2 += rbf[k + 2] * eW1[(k + 2) * 64 + h];
                    a3 += rbf[k + 3] * eW1[(k + 3) * 64 + h];
                }
                const float hv = silu(eb1[h] + ((a0 + a1) + (a2 + a3)));
                #pragma unroll
                for (int c = 0; c < EDGE_DIM; c += 4) {
                    const float4 w4 = *(const float4*)&eW2[h * 64 + c];
                    o[c]     += hv * w4.x;
                    o[c + 1] += hv * w4.y;
                    o[c + 2] += hv * w4.z;
                    o[c + 3] += hv * w4.w;
                }
            }

            f32x4* pp = (f32x4*)(rowp + (size_t)j * EDGE_DIM);
            #pragma unroll
            for (int q = 0; q < EDGE_DIM / 4; ++q) {
                f32x4 v = { o[4 * q] * mf, o[4 * q + 1] * mf,
                            o[4 * q + 2] * mf, o[4 * q + 3] * mf };
                __builtin_nontemporal_store(v, &pp[q]);
            }
        }
    } else {
        // ================= node path (2 residues per block) =================
        const int half = t >> 7;           // 0 or 1
        const int lt = t & 127;
        const int rblk = (blk - NROWS) * 2 + half;   // b*192 + r
        const int wt = wt_idx[rblk];
        const int mu = mut_idx[rblk];
        const float mm = mut_mask[rblk];

        float (&s_in)[128] = sm.n.in[half];
        float (&s_h)[128]  = sm.n.h[half];
        float (&s_res)[96] = sm.n.res[half];
        float (&s_nin)[128] = sm.n.nin[half];

        if (lt < 32) { s_in[lt] = aa_emb[wt * 32 + lt]; s_in[32 + lt] = aa_emb[mu * 32 + lt]; }
        if (lt < 30) { s_in[64 + lt] = aa_props[wt * 30 + lt]; s_in[94 + lt] = aa_props[mu * 30 + lt]; }
        __syncthreads();

        if (lt < 64) {
            float acc = mb1[lt];
            for (int k = 0; k < 124; ++k) acc += s_in[k] * mW1[k * 64 + lt];
            s_h[lt] = silu(acc);
        }
        __syncthreads();

        if (lt < 32) {
            float acc = mb2[lt];
            for (int k = 0; k < 64; ++k) acc += s_h[k] * mW2[k * 32 + lt];
            s_res[62 + lt] = acc * mm;
            s_res[lt] = s_in[lt];
        }
        if (lt < 30) s_res[32 + lt] = s_in[64 + lt];
        __syncthreads();

        for (int a = 0; a < 4; ++a) {
            const int gn = rblk * 4 + a;   // b*768 + n
            if (lt < 94) s_nin[lt] = s_res[lt];
            else if (lt < 110) s_nin[lt] = atom_emb[a * 16 + (lt - 94)];
            else if (lt < 126) s_nin[lt] = pos_emb[res_idx[gn] * 16 + (lt - 110)];
            __syncthreads();

            float acc = nb1[lt];
            for (int k = 0; k < 126; ++k) acc += s_nin[k] * nW1[k * 128 + lt];
            float h = silu(acc);
            __syncthreads();
            s_h[lt] = h;
            __syncthreads();

            float o = nb2[lt];
            for (int k = 0; k < 128; ++k) o += s_h[k] * nW2[k * 128 + lt];
            const float am = atom_mask[gn];
            out[NODE_OFF + (size_t)gn * 128 + lt] = o * am;
            __syncthreads();
        }

        if (lt < 12) out[COORDS_OFF + (size_t)rblk * 12 + lt] = coords[(size_t)rblk * 12 + lt];
        if (lt < 4)  out[MASK_OFF + (size_t)rblk * 4 + lt]  = atom_mask[(size_t)rblk * 4 + lt];
    }
}

extern "C" void kernel_launch(void* const* d_in, const int* in_sizes, int n_in,
                              void* d_out, int out_size, void* d_ws, size_t ws_size,
                              hipStream_t stream) {
    const float* coords    = (const float*)d_in[0];
    const float* mut_mask  = (const float*)d_in[1];
    const float* atom_mask = (const float*)d_in[2];
    const float* aa_emb    = (const float*)d_in[3];
    const float* atom_emb  = (const float*)d_in[4];
    const float* pos_emb   = (const float*)d_in[5];
    const float* aa_props  = (const float*)d_in[6];
    const float* mut_W1    = (const float*)d_in[7];
    const float* mut_b1    = (const float*)d_in[8];
    const float* mut_W2    = (const float*)d_in[9];
    const float* mut_b2    = (const float*)d_in[10];
    const float* node_W1   = (const float*)d_in[11];
    const float* node_b1   = (const float*)d_in[12];
    const float* node_W2   = (const float*)d_in[13];
    const float* node_b2   = (const float*)d_in[14];
    const float* edge_W1   = (const float*)d_in[15];
    const float* edge_b1   = (const float*)d_in[16];
    const float* edge_W2   = (const float*)d_in[17];
    const float* edge_b2   = (const float*)d_in[18];
    const int* wt_indices  = (const int*)d_in[19];
    const int* mut_indices = (const int*)d_in[20];
    const int* res_indices = (const int*)d_in[21];

    float* out = (float*)d_out;

    // 1) zero exactly the edge region (302.0 MB) at blit rate
    (void)hipMemsetAsync((char*)d_out + EDGE_OFF * 4, 0, EDGE_BYTES, stream);

    // 2) everything else in one dispatch: 1536 edge-row blocks + 192 node blocks
    fused_kernel<<<NROWS + NODE_BLOCKS, 256, 0, stream>>>(
        coords, mut_mask, atom_mask, aa_emb, atom_emb, pos_emb, aa_props,
        mut_W1, mut_b1, mut_W2, mut_b2, node_W1, node_b1, node_W2, node_b2,
        edge_W1, edge_b1, edge_W2, edge_b2,
        wt_indices, mut_indices, res_indices, out);
}